// Round 4
// baseline (1447.353 us; speedup 1.0000x reference)
//
#include <hip/hip_runtime.h>
#include <hip/hip_bf16.h>
#include <math.h>

#define VOCAB 32000
#define EMB   256
#define HID   512
#define BB    4
#define SS    512
#define G4H   2048   // 4*HID
#define BS    2048   // BB*SS

typedef unsigned int   u32;
typedef unsigned short u16;
using short8 = __attribute__((ext_vector_type(8))) short;
using f32x4  = __attribute__((ext_vector_type(4))) float;

// workspace layout (float units).  Region [0, 8192000) is time-shared:
//   xp (4194304 floats) lives from k1 until k2 completes,
//   then WB (32000*512 bf16 = 8192000 float-slots) overwrites it.
#define OFF_HSB  8192000ull   // hsaveB: 2048*512 bf16 = 524288 float-slots
#define OFF_HW   8716288ull   // hw: 2*4*512 u32 tagged h words = 4096 slots
#define OFF_SUM  8722432ull   // sumexp: 2048 floats
// end = 8724480 floats = 34.9 MB

__device__ inline unsigned packbf(float a, float b) {
    unsigned ua = __float_as_uint(a), ub = __float_as_uint(b);
    ua += 0x7fffu + ((ua >> 16) & 1u);
    ub += 0x7fffu + ((ub >> 16) & 1u);
    return (ua >> 16) | (ub & 0xffff0000u);
}

__device__ inline float fast_tanh(float x) {
    // tanh(x) = 1 - 2/(exp(2x)+1); exact at +-inf, ~1ulp-ish mid-range
    return 1.f - 2.f / (__expf(2.f * x) + 1.f);
}

#define GLOAD_LDS16(gp, lp) __builtin_amdgcn_global_load_lds( \
    (const __attribute__((address_space(1))) void*)(gp),      \
    (__attribute__((address_space(3))) void*)(lp), 16, 0, 0)

// ---------------------------------------------------------------------------
// k1: xp[bs][g] = sum_e emb[batch[bs]][e] * w_ih[g][e] + b_ih[g] + b_hh[g]
// ---------------------------------------------------------------------------
__global__ __launch_bounds__(256) void k_embed_xp(
    const int* __restrict__ batch, const float* __restrict__ emb,
    const float* __restrict__ w_ih, const float* __restrict__ b_ih,
    const float* __restrict__ b_hh, float* __restrict__ xp)
{
    __shared__ float Asl[16 * 64];
    __shared__ float Bsl[16 * 64];
    const int tid = threadIdx.x;
    const int bs0 = blockIdx.x * 64;
    const int g0  = blockIdx.y * 64;
    const int m  = tid & 63;
    const int kg = tid >> 6;
    const int tok = batch[bs0 + m];
    const float* arow = emb + (size_t)tok * EMB;
    const float* brow = w_ih + (size_t)(g0 + m) * EMB;
    const int tm = tid >> 4;
    const int tv = tid & 15;

    float acc[4][4] = {};
    for (int k0 = 0; k0 < EMB; k0 += 16) {
        float4 a4 = *(const float4*)(arow + k0 + kg * 4);
        float4 b4 = *(const float4*)(brow + k0 + kg * 4);
        __syncthreads();
        const int kb = kg * 4;
        Asl[(kb + 0) * 64 + m] = a4.x;
        Asl[(kb + 1) * 64 + m] = a4.y;
        Asl[(kb + 2) * 64 + m] = a4.z;
        Asl[(kb + 3) * 64 + m] = a4.w;
        Bsl[(kb + 0) * 64 + m] = b4.x;
        Bsl[(kb + 1) * 64 + m] = b4.y;
        Bsl[(kb + 2) * 64 + m] = b4.z;
        Bsl[(kb + 3) * 64 + m] = b4.w;
        __syncthreads();
#pragma unroll
        for (int k = 0; k < 16; ++k) {
            float4 av = *(const float4*)&Asl[k * 64 + tm * 4];
            float4 bv = *(const float4*)&Bsl[k * 64 + tv * 4];
            float a[4] = {av.x, av.y, av.z, av.w};
            float bb[4] = {bv.x, bv.y, bv.z, bv.w};
#pragma unroll
            for (int i = 0; i < 4; ++i)
#pragma unroll
                for (int j = 0; j < 4; ++j)
                    acc[i][j] += a[i] * bb[j];
        }
    }
    float bsum[4];
#pragma unroll
    for (int j = 0; j < 4; ++j) {
        int g = g0 + tv * 4 + j;
        bsum[j] = b_ih[g] + b_hh[g];
    }
#pragma unroll
    for (int i = 0; i < 4; ++i) {
        int row = bs0 + tm * 4 + i;
        float4 o;
        o.x = acc[i][0] + bsum[0];
        o.y = acc[i][1] + bsum[1];
        o.z = acc[i][2] + bsum[2];
        o.w = acc[i][3] + bsum[3];
        *(float4*)(xp + (size_t)row * G4H + g0 + tv * 4) = o;
    }
}

// ---------------------------------------------------------------------------
// k2: persistent LSTM, tagged-word h exchange, single-barrier step.
// 128 WGs x 512 thr: WG = chain (wg>>5) x slice (wg&31); slice owns 16 hidden
// units -> 64 gate rows. Thread (u,g,q): u=tid>>5 unit, g=(tid>>3)&3 gate,
// q=tid&7 eighth of the K dim (64 h elems). w_hh in registers (packed bf16).
// h word = (bf16(h)<<16 | step tag), double-buffered by parity; producer does
// ONE fire-and-forget relaxed-agent store; consumers poll the word itself.
// Per step: poll -> hl[parity] fill -> ONE barrier -> dot -> shfl reduce ->
// parallel tail (16 lanes across all 8 waves) -> store. xp read into register
// by q==0 lanes only (waitcnt sinks below the poll -> latency hidden).
// ---------------------------------------------------------------------------
__global__ __launch_bounds__(512) void k_lstm(
    const float* __restrict__ w_hh, const float* __restrict__ xp,
    u32* __restrict__ hw, u16* __restrict__ hsaveB)
{
    __shared__ float hl[2][8 * 68];   // [parity][eighth*68 + idx], stride 68:
                                      // conflict-free b128 reads + 16B aligned

    const int tid   = threadIdx.x;
    const int wg    = blockIdx.x;      // 128 WGs
    const int c     = wg >> 5;         // chain 0..3
    const int slice = wg & 31;
    const int j0    = slice * 16;
    const int u     = tid >> 5;        // unit 0..15
    const int g     = (tid >> 3) & 3;  // gate i,f,g,o
    const int q     = tid & 7;         // K-eighth
    const int lane  = tid & 63;
    const int grow  = g * HID + j0 + u;

    // preload this thread's 64 w_hh values as packed bf16 (32 VGPRs)
    unsigned wreg[32];
    {
        const float* wsrc = w_hh + (size_t)grow * HID + q * 64;
#pragma unroll
        for (int i = 0; i < 16; ++i) {
            float4 f = *(const float4*)(wsrc + i * 4);
            wreg[2 * i]     = packbf(f.x, f.y);
            wreg[2 * i + 1] = packbf(f.z, f.w);
        }
    }

    float cst = 0.f;                   // cell state (lanes with (lane&31)==0)

    for (int t = 0; t < SS; ++t) {
        const int p = t & 1;
        // xp gate sum for this row -> register (q==0 lanes only)
        float xsv = 0.f;
        if (q == 0)
            xsv = xp[(size_t)(c * SS + t) * G4H + grow];
        // poll tagged h word for element `tid` of this chain
        u32 w;
        {
            u32* addr = hw + p * (BB * HID) + c * HID + tid;
            int guard = 0;
            for (;;) {
                w = __hip_atomic_load(addr, __ATOMIC_RELAXED,
                                      __HIP_MEMORY_SCOPE_AGENT);
                if ((w & 0xffffu) == (u32)t) break;
                __builtin_amdgcn_s_sleep(1);
                if (++guard > 2000000) break;
            }
        }
        hl[p][(tid >> 6) * 68 + (tid & 63)] = __uint_as_float(w & 0xffff0000u);
        __syncthreads();

        // 64-element partial dot: row grow, eighth q
        float acc = 0.f;
        {
            const float4* h4 = (const float4*)&hl[p][q * 68];
#pragma unroll
            for (int k = 0; k < 16; ++k) {
                float4 hv = h4[k];
                unsigned wa = wreg[2 * k], wb = wreg[2 * k + 1];
                acc = fmaf(hv.x, __uint_as_float(wa << 16), acc);
                acc = fmaf(hv.y, __uint_as_float(wa & 0xffff0000u), acc);
                acc = fmaf(hv.z, __uint_as_float(wb << 16), acc);
                acc = fmaf(hv.w, __uint_as_float(wb & 0xffff0000u), acc);
            }
        }
        // reduce the 8 K-eighths (lanes q=0..7 adjacent)
        acc += __shfl_xor(acc, 1);
        acc += __shfl_xor(acc, 2);
        acc += __shfl_xor(acc, 4);
        acc += xsv;                    // valid in q==0 lanes (gather sources)
        // gather the 4 gate sums of this half-wave's unit
        const int base = lane & 32;
        float s_i = __shfl(acc, base + 0);
        float s_f = __shfl(acc, base + 8);
        float s_g = __shfl(acc, base + 16);
        float s_o = __shfl(acc, base + 24);
        if ((lane & 31) == 0) {        // 2 lead lanes/wave, 16 total = 16 units
            float si = 1.f / (1.f + __expf(-s_i));
            float sf = 1.f / (1.f + __expf(-s_f));
            float so = 1.f / (1.f + __expf(-s_o));
            cst = sf * cst + si * fast_tanh(s_g);
            float hv = so * fast_tanh(cst);
            unsigned uu = __float_as_uint(hv);
            uu += 0x7fffu + ((uu >> 16) & 1u);
            uu &= 0xffff0000u;         // bf16 bits in hi16
            __hip_atomic_store(hw + (p ^ 1) * (BB * HID) + c * HID + j0 + u,
                               uu | (u32)(t + 1), __ATOMIC_RELAXED,
                               __HIP_MEMORY_SCOPE_AGENT);
            hsaveB[(size_t)(c * SS + t) * HID + j0 + u] = (u16)(uu >> 16);
        }
        // no trailing barrier: hl is parity-double-buffered; a wave cannot
        // reach step t+2 (rewriting hl[p]) before every wave passed t+1's
        // barrier, which postdates their step-t hl[p] reads.
    }
}

// ---------------------------------------------------------------------------
// wcvt: W fp32 -> bf16 (RNE), 16.384M elems
// ---------------------------------------------------------------------------
__global__ __launch_bounds__(256) void k_wcvt(
    const float* __restrict__ W, u16* __restrict__ WB)
{
    int i = blockIdx.x * 256 + threadIdx.x;
    float4 f = ((const float4*)W)[i];
    uint2 o;
    o.x = packbf(f.x, f.y);
    o.y = packbf(f.z, f.w);
    ((uint2*)WB)[i] = o;
}

// ---------------------------------------------------------------------------
// k3: bf16 MFMA logits + fused exp/row-sum -> sumexp.
// 128x128 tile, BK=64, global_load_lds(16B) with chunk-XOR swizzle.
// ---------------------------------------------------------------------------
__global__ __launch_bounds__(256) void k_logits_lse(
    const u16* __restrict__ hsaveB, const u16* __restrict__ WB,
    const float* __restrict__ bias, float* __restrict__ sumexp)
{
    __shared__ u16 As[128 * 64];
    __shared__ u16 Bs[128 * 64];
    const int tid  = threadIdx.x;
    const int lane = tid & 63;
    const int wave = tid >> 6;
    const int wr   = wave >> 1;
    const int wc   = wave & 1;
    const int bs0  = blockIdx.x * 128;
    const int v0   = blockIdx.y * 128;
    const int lr   = lane & 15;
    const int lc   = lane >> 4;

    f32x4 acc[4][4];
#pragma unroll
    for (int m = 0; m < 4; ++m)
#pragma unroll
        for (int n = 0; n < 4; ++n)
            acc[m][n] = (f32x4){0.f, 0.f, 0.f, 0.f};

    for (int k0 = 0; k0 < HID; k0 += 64) {
#pragma unroll
        for (int it = 0; it < 4; ++it) {
            int base = it * 256 + wave * 64;
            int idx  = base + lane;
            int row  = idx >> 3, cl = idx & 7;
            int gcl  = cl ^ (row & 7);
            const u16* gA = hsaveB + (size_t)(bs0 + row) * HID + k0 + gcl * 8;
            GLOAD_LDS16(gA, As + (size_t)base * 8);
            const u16* gB = WB + (size_t)(v0 + row) * HID + k0 + gcl * 8;
            GLOAD_LDS16(gB, Bs + (size_t)base * 8);
        }
        asm volatile("s_waitcnt vmcnt(0)" ::: "memory");
        __syncthreads();

        short8 af[4][2], bf[4][2];
#pragma unroll
        for (int m = 0; m < 4; ++m)
#pragma unroll
            for (int ks = 0; ks < 2; ++ks) {
                int rowA = wr * 64 + m * 16 + lr;
                int swa  = ((ks * 4 + lc) ^ (rowA & 7)) * 8;
                af[m][ks] = *(const short8*)&As[rowA * 64 + swa];
                int rowB = wc * 64 + m * 16 + lr;
                int swb  = ((ks * 4 + lc) ^ (rowB & 7)) * 8;
                bf[m][ks] = *(const short8*)&Bs[rowB * 64 + swb];
            }
#pragma unroll
        for (int m = 0; m < 4; ++m)
#pragma unroll
            for (int n = 0; n < 4; ++n)
#pragma unroll
                for (int ks = 0; ks < 2; ++ks)
                    acc[m][n] = __builtin_amdgcn_mfma_f32_16x16x32_bf16(
                        af[m][ks], bf[n][ks], acc[m][n], 0, 0, 0);
        __syncthreads();
    }

    float bn[4];
#pragma unroll
    for (int n = 0; n < 4; ++n)
        bn[n] = bias[v0 + wc * 64 + n * 16 + lr];

#pragma unroll
    for (int m = 0; m < 4; ++m) {
        float p0 = 0.f, p1 = 0.f, p2 = 0.f, p3 = 0.f;
#pragma unroll
        for (int n = 0; n < 4; ++n) {
            float b = bn[n];
            p0 += __expf(acc[m][n][0] + b);
            p1 += __expf(acc[m][n][1] + b);
            p2 += __expf(acc[m][n][2] + b);
            p3 += __expf(acc[m][n][3] + b);
        }
#pragma unroll
        for (int off = 1; off < 16; off <<= 1) {
            p0 += __shfl_xor(p0, off);
            p1 += __shfl_xor(p1, off);
            p2 += __shfl_xor(p2, off);
            p3 += __shfl_xor(p3, off);
        }
        if (lr == 0) {
            int row = bs0 + wr * 64 + m * 16 + lc * 4;
            atomicAdd(&sumexp[row + 0], p0);
            atomicAdd(&sumexp[row + 1], p1);
            atomicAdd(&sumexp[row + 2], p2);
            atomicAdd(&sumexp[row + 3], p3);
        }
    }
}

// ---------------------------------------------------------------------------
// k4: one wave per (b,s): decode contiguous-view gather, recompute picked
// logit (bf16), subtract log(sumexp), accumulate -mean.
// ---------------------------------------------------------------------------
__device__ inline float dotp(u32 h, u32 w) {
    return __uint_as_float(h << 16) * __uint_as_float(w << 16) +
           __uint_as_float(h & 0xffff0000u) * __uint_as_float(w & 0xffff0000u);
}

__global__ __launch_bounds__(256) void k_final(
    const int* __restrict__ batch, const u16* __restrict__ hsaveB,
    const u16* __restrict__ WB, const float* __restrict__ bias,
    const float* __restrict__ sumexp, float* __restrict__ out)
{
    const int gt   = blockIdx.x * 256 + threadIdx.x;
    const int wid  = gt >> 6;
    const int lane = gt & 63;
    const unsigned tgt = (unsigned)batch[wid];
    const unsigned s2 = wid >> 2, b2 = wid & 3;
    const unsigned j = s2 * (VOCAB * BB) + tgt * BB + b2;
    const unsigned SV = (unsigned)SS * VOCAB;
    const unsigned b_o = j / SV;
    const unsigned rr = j - b_o * SV;
    const unsigned s_o = rr / VOCAB;
    const unsigned v_o = rr - s_o * VOCAB;
    const unsigned row = b_o * SS + s_o;

    uint4 hu = *(const uint4*)(hsaveB + (size_t)row * HID + lane * 8);
    uint4 wu = *(const uint4*)(WB + (size_t)v_o * HID + lane * 8);
    float d = dotp(hu.x, wu.x) + dotp(hu.y, wu.y) +
              dotp(hu.z, wu.z) + dotp(hu.w, wu.w);
#pragma unroll
    for (int off = 32; off >= 1; off >>= 1)
        d += __shfl_xor(d, off);
    if (lane == 0) {
        float picked = d + bias[v_o] - logf(sumexp[row]);
        atomicAdd(out, -picked * (1.f / (float)BS));
    }
}

// ---------------------------------------------------------------------------
extern "C" void kernel_launch(void* const* d_in, const int* in_sizes, int n_in,
                              void* d_out, int out_size, void* d_ws, size_t ws_size,
                              hipStream_t stream)
{
    const int*   batch = (const int*)d_in[0];
    const float* emb   = (const float*)d_in[1];
    const float* w_ih  = (const float*)d_in[2];
    const float* w_hh  = (const float*)d_in[3];
    const float* b_ih  = (const float*)d_in[4];
    const float* b_hh  = (const float*)d_in[5];
    const float* Wm    = (const float*)d_in[6];
    const float* bvec  = (const float*)d_in[7];
    float* out = (float*)d_out;
    float* ws  = (float*)d_ws;

    float* xp      = ws;                       // dead after k2
    u16*   WB      = (u16*)ws;                 // written after k2 (time-shared)
    u16*   hsaveB  = (u16*)(ws + OFF_HSB);
    u32*   hw      = (u32*)(ws + OFF_HW);
    float* sumexp  = ws + OFF_SUM;

    // zero hw (+slack) + sumexp (contiguous) and out
    hipMemsetAsync(hw, 0, (4096 + 2048 + 2048) * sizeof(float), stream);
    hipMemsetAsync(out, 0, sizeof(float), stream);

    dim3 g1(BS / 64, G4H / 64);
    k_embed_xp<<<g1, 256, 0, stream>>>(batch, emb, w_ih, b_ih, b_hh, xp);

    k_lstm<<<128, 512, 0, stream>>>(w_hh, xp, hw, hsaveB);

    k_wcvt<<<VOCAB * HID / 4 / 256, 256, 0, stream>>>(Wm, WB);

    dim3 g3(BS / 128, VOCAB / 128);
    k_logits_lse<<<g3, 256, 0, stream>>>(hsaveB, WB, bvec, sumexp);

    k_final<<<BS * 64 / 256, 256, 0, stream>>>(batch, hsaveB, WB, bvec, sumexp, out);
}

// Round 5
// 1348.092 us; speedup vs baseline: 1.0736x; 1.0736x over previous
//
#include <hip/hip_runtime.h>
#include <hip/hip_bf16.h>
#include <math.h>

#define VOCAB 32000
#define EMB   256
#define HID   512
#define BB    4
#define SS    512
#define G4H   2048   // 4*HID
#define BS    2048   // BB*SS

typedef unsigned int   u32;
typedef unsigned short u16;
using short8 = __attribute__((ext_vector_type(8))) short;
using f32x4  = __attribute__((ext_vector_type(4))) float;

// workspace layout (float units).  Region [0, 8192000) is time-shared:
//   xp (4194304 floats, WG-local layout) lives from k1 until k2 completes,
//   then WB (32000*512 bf16 = 8192000 float-slots) overwrites it.
#define OFF_HSB  8192000ull   // hsaveB: 2048*512 bf16 = 524288 float-slots
#define OFF_HW   8716288ull   // hw: 2*4*512 u32 tagged h words = 4096 slots
#define OFF_SUM  8722432ull   // sumexp: 2048 floats
// end = 8724480 floats = 34.9 MB

__device__ inline unsigned packbf(float a, float b) {
    unsigned ua = __float_as_uint(a), ub = __float_as_uint(b);
    ua += 0x7fffu + ((ua >> 16) & 1u);
    ub += 0x7fffu + ((ub >> 16) & 1u);
    return (ua >> 16) | (ub & 0xffff0000u);
}

__device__ inline float fast_tanh(float x) {
    // tanh(x) = 1 - 2/(exp(2x)+1); exact at +-inf
    return 1.f - 2.f / (__expf(2.f * x) + 1.f);
}

#define GLOAD_LDS16(gp, lp) __builtin_amdgcn_global_load_lds( \
    (const __attribute__((address_space(1))) void*)(gp),      \
    (__attribute__((address_space(3))) void*)(lp), 16, 0, 0)

// ---------------------------------------------------------------------------
// k1: xp = embeds @ w_ih^T + b_ih + b_hh, written in k2's WG-local layout:
//   xp2[ ((c*16 + slice)*SS + t)*128 + g*32 + (j&31) ]
// where c=chain, t=step, slice=j>>5 (j = hidden unit), g = gate.
// Each k2 WG then reads one contiguous 512B block per step.
// ---------------------------------------------------------------------------
__global__ __launch_bounds__(256) void k_embed_xp(
    const int* __restrict__ batch, const float* __restrict__ emb,
    const float* __restrict__ w_ih, const float* __restrict__ b_ih,
    const float* __restrict__ b_hh, float* __restrict__ xp)
{
    __shared__ float Asl[16 * 64];
    __shared__ float Bsl[16 * 64];
    const int tid = threadIdx.x;
    const int bs0 = blockIdx.x * 64;
    const int g0  = blockIdx.y * 64;
    const int m  = tid & 63;
    const int kg = tid >> 6;
    const int tok = batch[bs0 + m];
    const float* arow = emb + (size_t)tok * EMB;
    const float* brow = w_ih + (size_t)(g0 + m) * EMB;
    const int tm = tid >> 4;
    const int tv = tid & 15;

    float acc[4][4] = {};
    for (int k0 = 0; k0 < EMB; k0 += 16) {
        float4 a4 = *(const float4*)(arow + k0 + kg * 4);
        float4 b4 = *(const float4*)(brow + k0 + kg * 4);
        __syncthreads();
        const int kb = kg * 4;
        Asl[(kb + 0) * 64 + m] = a4.x;
        Asl[(kb + 1) * 64 + m] = a4.y;
        Asl[(kb + 2) * 64 + m] = a4.z;
        Asl[(kb + 3) * 64 + m] = a4.w;
        Bsl[(kb + 0) * 64 + m] = b4.x;
        Bsl[(kb + 1) * 64 + m] = b4.y;
        Bsl[(kb + 2) * 64 + m] = b4.z;
        Bsl[(kb + 3) * 64 + m] = b4.w;
        __syncthreads();
#pragma unroll
        for (int k = 0; k < 16; ++k) {
            float4 av = *(const float4*)&Asl[k * 64 + tm * 4];
            float4 bv = *(const float4*)&Bsl[k * 64 + tv * 4];
            float a[4] = {av.x, av.y, av.z, av.w};
            float bb[4] = {bv.x, bv.y, bv.z, bv.w};
#pragma unroll
            for (int i = 0; i < 4; ++i)
#pragma unroll
                for (int j = 0; j < 4; ++j)
                    acc[i][j] += a[i] * bb[j];
        }
    }
    float bsum[4];
#pragma unroll
    for (int j = 0; j < 4; ++j) {
        int g = g0 + tv * 4 + j;
        bsum[j] = b_ih[g] + b_hh[g];
    }
    const int cg = g0 + tv * 4;          // gate-column of element 0
    const int gg = cg >> 9;              // gate 0..3
    const int jj = cg & 511;             // hidden unit
    const int sl = jj >> 5;              // slice
    const int li = jj & 31;              // unit within slice (li+3 stays <32)
#pragma unroll
    for (int i = 0; i < 4; ++i) {
        int row = bs0 + tm * 4 + i;
        int cch = row >> 9, tt = row & 511;
        float4 o;
        o.x = acc[i][0] + bsum[0];
        o.y = acc[i][1] + bsum[1];
        o.z = acc[i][2] + bsum[2];
        o.w = acc[i][3] + bsum[3];
        *(float4*)(xp + ((size_t)(cch * 16 + sl) * SS + tt) * 128 +
                   gg * 32 + li) = o;
    }
}

// ---------------------------------------------------------------------------
// k2: persistent LSTM, tagged-word h exchange, single-barrier step.
// 64 WGs x 512 thr: WG = chain (wg>>4) x slice (wg&15); slice owns 32 hidden
// units -> 128 gate rows. Thread (u,g,q): u=tid>>4 unit, g=(tid>>2)&3 gate,
// q=tid&3 K-quarter (128 h elems). w_hh in registers (packed bf16).
// h word = (bf16(h)<<16 | step tag), parity double-buffered; producer does
// ONE fire-and-forget relaxed-agent store; consumers poll the word itself.
// Per step: poll -> hl[parity] fill -> ONE barrier -> dot -> shfl reduce ->
// tail (4 lanes per wave, 32 total) -> store. xp read is one contiguous
// 512B block per WG per step (latency hidden under the poll).
// ---------------------------------------------------------------------------
__global__ __launch_bounds__(512) void k_lstm(
    const float* __restrict__ w_hh, const float* __restrict__ xp2,
    u32* __restrict__ hw, u16* __restrict__ hsaveB)
{
    __shared__ float hl[2][4 * 132];   // [parity][quarter*132 + idx]

    const int tid   = threadIdx.x;
    const int wg    = blockIdx.x;      // 64 WGs
    const int c     = wg >> 4;         // chain 0..3
    const int slice = wg & 15;
    const int j0    = slice * 32;
    const int u     = tid >> 4;        // unit 0..31
    const int g     = (tid >> 2) & 3;  // gate i,f,g,o
    const int q     = tid & 3;         // K-quarter
    const int lane  = tid & 63;
    const int grow  = g * HID + j0 + u;

    // preload this thread's 128 w_hh values as packed bf16 (64 VGPRs)
    unsigned wreg[64];
    {
        const float* wsrc = w_hh + (size_t)grow * HID + q * 128;
#pragma unroll
        for (int i = 0; i < 32; ++i) {
            float4 f = *(const float4*)(wsrc + i * 4);
            wreg[2 * i]     = packbf(f.x, f.y);
            wreg[2 * i + 1] = packbf(f.z, f.w);
        }
    }

    const float* xbase = xp2 + (size_t)(c * 16 + slice) * (SS * 128) +
                         g * 32 + u;
    float cst = 0.f;                   // cell state (lanes with (lane&15)==0)

    for (int t = 0; t < SS; ++t) {
        const int p = t & 1;
        // per-row xp gate sum (same addr in all 4 q-lanes -> broadcast)
        float xsv = xbase[t * 128];
        // poll tagged h word for element `tid` of this chain
        u32 w;
        {
            u32* addr = hw + p * (BB * HID) + c * HID + tid;
            int guard = 0;
            for (;;) {
                w = __hip_atomic_load(addr, __ATOMIC_RELAXED,
                                      __HIP_MEMORY_SCOPE_AGENT);
                if ((w & 0xffffu) == (u32)t) break;
                __builtin_amdgcn_s_sleep(1);
                if (++guard > 2000000) break;
            }
        }
        hl[p][(tid >> 7) * 132 + (tid & 127)] = __uint_as_float(w & 0xffff0000u);
        __syncthreads();

        // 128-element partial dot: row grow, quarter q
        float acc = 0.f;
        {
            const float4* h4 = (const float4*)&hl[p][q * 132];
#pragma unroll
            for (int k = 0; k < 32; ++k) {
                float4 hv = h4[k];
                unsigned wa = wreg[2 * k], wb = wreg[2 * k + 1];
                acc = fmaf(hv.x, __uint_as_float(wa << 16), acc);
                acc = fmaf(hv.y, __uint_as_float(wa & 0xffff0000u), acc);
                acc = fmaf(hv.z, __uint_as_float(wb << 16), acc);
                acc = fmaf(hv.w, __uint_as_float(wb & 0xffff0000u), acc);
            }
        }
        // reduce the 4 K-quarters (lanes q=0..3 adjacent); all lanes get sum
        acc += __shfl_xor(acc, 1);
        acc += __shfl_xor(acc, 2);
        acc += xsv;
        // gather the 4 gate sums of this lane's unit (16 lanes per unit)
        const int base = lane & 48;
        float s_i = __shfl(acc, base + 0);
        float s_f = __shfl(acc, base + 4);
        float s_g = __shfl(acc, base + 8);
        float s_o = __shfl(acc, base + 12);
        if ((lane & 15) == 0) {        // 4 tail lanes/wave, 32 total
            float si = 1.f / (1.f + __expf(-s_i));
            float sf = 1.f / (1.f + __expf(-s_f));
            float so = 1.f / (1.f + __expf(-s_o));
            cst = sf * cst + si * fast_tanh(s_g);
            float hv = so * fast_tanh(cst);
            unsigned uu = __float_as_uint(hv);
            uu += 0x7fffu + ((uu >> 16) & 1u);
            uu &= 0xffff0000u;         // bf16 bits in hi16
            __hip_atomic_store(hw + (p ^ 1) * (BB * HID) + c * HID + j0 + u,
                               uu | (u32)(t + 1), __ATOMIC_RELAXED,
                               __HIP_MEMORY_SCOPE_AGENT);
            hsaveB[(size_t)(c * SS + t) * HID + j0 + u] = (u16)(uu >> 16);
        }
        // no trailing barrier: hl is parity-double-buffered; a wave cannot
        // reach step t+2 (rewriting hl[p]) before every wave passed t+1's
        // barrier, which postdates their step-t hl[p] reads.
    }
}

// ---------------------------------------------------------------------------
// wcvt: W fp32 -> bf16 (RNE), 16.384M elems
// ---------------------------------------------------------------------------
__global__ __launch_bounds__(256) void k_wcvt(
    const float* __restrict__ W, u16* __restrict__ WB)
{
    int i = blockIdx.x * 256 + threadIdx.x;
    float4 f = ((const float4*)W)[i];
    uint2 o;
    o.x = packbf(f.x, f.y);
    o.y = packbf(f.z, f.w);
    ((uint2*)WB)[i] = o;
}

// ---------------------------------------------------------------------------
// k3: bf16 MFMA logits + fused exp/row-sum -> sumexp.
// 128x128 tile, BK=64, global_load_lds(16B) with chunk-XOR swizzle.
// ---------------------------------------------------------------------------
__global__ __launch_bounds__(256) void k_logits_lse(
    const u16* __restrict__ hsaveB, const u16* __restrict__ WB,
    const float* __restrict__ bias, float* __restrict__ sumexp)
{
    __shared__ u16 As[128 * 64];
    __shared__ u16 Bs[128 * 64];
    const int tid  = threadIdx.x;
    const int lane = tid & 63;
    const int wave = tid >> 6;
    const int wr   = wave >> 1;
    const int wc   = wave & 1;
    const int bs0  = blockIdx.x * 128;
    const int v0   = blockIdx.y * 128;
    const int lr   = lane & 15;
    const int lc   = lane >> 4;

    f32x4 acc[4][4];
#pragma unroll
    for (int m = 0; m < 4; ++m)
#pragma unroll
        for (int n = 0; n < 4; ++n)
            acc[m][n] = (f32x4){0.f, 0.f, 0.f, 0.f};

    for (int k0 = 0; k0 < HID; k0 += 64) {
#pragma unroll
        for (int it = 0; it < 4; ++it) {
            int base = it * 256 + wave * 64;
            int idx  = base + lane;
            int row  = idx >> 3, cl = idx & 7;
            int gcl  = cl ^ (row & 7);
            const u16* gA = hsaveB + (size_t)(bs0 + row) * HID + k0 + gcl * 8;
            GLOAD_LDS16(gA, As + (size_t)base * 8);
            const u16* gB = WB + (size_t)(v0 + row) * HID + k0 + gcl * 8;
            GLOAD_LDS16(gB, Bs + (size_t)base * 8);
        }
        asm volatile("s_waitcnt vmcnt(0)" ::: "memory");
        __syncthreads();

        short8 af[4][2], bf[4][2];
#pragma unroll
        for (int m = 0; m < 4; ++m)
#pragma unroll
            for (int ks = 0; ks < 2; ++ks) {
                int rowA = wr * 64 + m * 16 + lr;
                int swa  = ((ks * 4 + lc) ^ (rowA & 7)) * 8;
                af[m][ks] = *(const short8*)&As[rowA * 64 + swa];
                int rowB = wc * 64 + m * 16 + lr;
                int swb  = ((ks * 4 + lc) ^ (rowB & 7)) * 8;
                bf[m][ks] = *(const short8*)&Bs[rowB * 64 + swb];
            }
#pragma unroll
        for (int m = 0; m < 4; ++m)
#pragma unroll
            for (int n = 0; n < 4; ++n)
#pragma unroll
                for (int ks = 0; ks < 2; ++ks)
                    acc[m][n] = __builtin_amdgcn_mfma_f32_16x16x32_bf16(
                        af[m][ks], bf[n][ks], acc[m][n], 0, 0, 0);
        __syncthreads();
    }

    float bn[4];
#pragma unroll
    for (int n = 0; n < 4; ++n)
        bn[n] = bias[v0 + wc * 64 + n * 16 + lr];

#pragma unroll
    for (int m = 0; m < 4; ++m) {
        float p0 = 0.f, p1 = 0.f, p2 = 0.f, p3 = 0.f;
#pragma unroll
        for (int n = 0; n < 4; ++n) {
            float b = bn[n];
            p0 += __expf(acc[m][n][0] + b);
            p1 += __expf(acc[m][n][1] + b);
            p2 += __expf(acc[m][n][2] + b);
            p3 += __expf(acc[m][n][3] + b);
        }
#pragma unroll
        for (int off = 1; off < 16; off <<= 1) {
            p0 += __shfl_xor(p0, off);
            p1 += __shfl_xor(p1, off);
            p2 += __shfl_xor(p2, off);
            p3 += __shfl_xor(p3, off);
        }
        if (lr == 0) {
            int row = bs0 + wr * 64 + m * 16 + lc * 4;
            atomicAdd(&sumexp[row + 0], p0);
            atomicAdd(&sumexp[row + 1], p1);
            atomicAdd(&sumexp[row + 2], p2);
            atomicAdd(&sumexp[row + 3], p3);
        }
    }
}

// ---------------------------------------------------------------------------
// k4: one wave per (b,s): decode contiguous-view gather, recompute picked
// logit (bf16), subtract log(sumexp), accumulate -mean.
// ---------------------------------------------------------------------------
__device__ inline float dotp(u32 h, u32 w) {
    return __uint_as_float(h << 16) * __uint_as_float(w << 16) +
           __uint_as_float(h & 0xffff0000u) * __uint_as_float(w & 0xffff0000u);
}

__global__ __launch_bounds__(256) void k_final(
    const int* __restrict__ batch, const u16* __restrict__ hsaveB,
    const u16* __restrict__ WB, const float* __restrict__ bias,
    const float* __restrict__ sumexp, float* __restrict__ out)
{
    const int gt   = blockIdx.x * 256 + threadIdx.x;
    const int wid  = gt >> 6;
    const int lane = gt & 63;
    const unsigned tgt = (unsigned)batch[wid];
    const unsigned s2 = wid >> 2, b2 = wid & 3;
    const unsigned j = s2 * (VOCAB * BB) + tgt * BB + b2;
    const unsigned SV = (unsigned)SS * VOCAB;
    const unsigned b_o = j / SV;
    const unsigned rr = j - b_o * SV;
    const unsigned s_o = rr / VOCAB;
    const unsigned v_o = rr - s_o * VOCAB;
    const unsigned row = b_o * SS + s_o;

    uint4 hu = *(const uint4*)(hsaveB + (size_t)row * HID + lane * 8);
    uint4 wu = *(const uint4*)(WB + (size_t)v_o * HID + lane * 8);
    float d = dotp(hu.x, wu.x) + dotp(hu.y, wu.y) +
              dotp(hu.z, wu.z) + dotp(hu.w, wu.w);
#pragma unroll
    for (int off = 32; off >= 1; off >>= 1)
        d += __shfl_xor(d, off);
    if (lane == 0) {
        float picked = d + bias[v_o] - logf(sumexp[row]);
        atomicAdd(out, -picked * (1.f / (float)BS));
    }
}

// ---------------------------------------------------------------------------
extern "C" void kernel_launch(void* const* d_in, const int* in_sizes, int n_in,
                              void* d_out, int out_size, void* d_ws, size_t ws_size,
                              hipStream_t stream)
{
    const int*   batch = (const int*)d_in[0];
    const float* emb   = (const float*)d_in[1];
    const float* w_ih  = (const float*)d_in[2];
    const float* w_hh  = (const float*)d_in[3];
    const float* b_ih  = (const float*)d_in[4];
    const float* b_hh  = (const float*)d_in[5];
    const float* Wm    = (const float*)d_in[6];
    const float* bvec  = (const float*)d_in[7];
    float* out = (float*)d_out;
    float* ws  = (float*)d_ws;

    float* xp      = ws;                       // dead after k2
    u16*   WB      = (u16*)ws;                 // written after k2 (time-shared)
    u16*   hsaveB  = (u16*)(ws + OFF_HSB);
    u32*   hw      = (u32*)(ws + OFF_HW);
    float* sumexp  = ws + OFF_SUM;

    // zero hw (+slack) + sumexp (contiguous) and out
    hipMemsetAsync(hw, 0, (4096 + 2048 + 2048) * sizeof(float), stream);
    hipMemsetAsync(out, 0, sizeof(float), stream);

    dim3 g1(BS / 64, G4H / 64);
    k_embed_xp<<<g1, 256, 0, stream>>>(batch, emb, w_ih, b_ih, b_hh, xp);

    k_lstm<<<64, 512, 0, stream>>>(w_hh, xp, hw, hsaveB);

    k_wcvt<<<VOCAB * HID / 4 / 256, 256, 0, stream>>>(Wm, WB);

    dim3 g3(BS / 128, VOCAB / 128);
    k_logits_lse<<<g3, 256, 0, stream>>>(hsaveB, WB, bvec, sumexp);

    k_final<<<BS * 64 / 256, 256, 0, stream>>>(batch, hsaveB, WB, bvec, sumexp, out);
}

// Round 6
// 1145.332 us; speedup vs baseline: 1.2637x; 1.1770x over previous
//
#include <hip/hip_runtime.h>
#include <hip/hip_bf16.h>
#include <math.h>

#define VOCAB 32000
#define EMB   256
#define HID   512
#define BB    4
#define SS    512
#define G4H   2048   // 4*HID
#define BS    2048   // BB*SS

typedef unsigned int   u32;
typedef unsigned short u16;
using short8 = __attribute__((ext_vector_type(8))) short;
using f32x4  = __attribute__((ext_vector_type(4))) float;

// workspace layout (float units).  Region [0, 8192000) is time-shared:
//   xp (4194304 floats, WG-local layout) lives from k1 until k2 completes,
//   then WB (32000*512 bf16 = 8192000 float-slots) overwrites it.
#define OFF_HSB  8192000ull   // hsaveB: 2048*512 bf16 = 524288 float-slots
#define OFF_HW   8716288ull   // hw: 2*4*512 u32 tagged h words = 4096 slots
#define OFF_SUM  8722432ull   // sumexp: 2048 floats
// end = 8724480 floats = 34.9 MB

__device__ inline unsigned packbf(float a, float b) {
    unsigned ua = __float_as_uint(a), ub = __float_as_uint(b);
    ua += 0x7fffu + ((ua >> 16) & 1u);
    ub += 0x7fffu + ((ub >> 16) & 1u);
    return (ua >> 16) | (ub & 0xffff0000u);
}

__device__ inline float lo16(unsigned w) { return __uint_as_float(w << 16); }
__device__ inline float hi16(unsigned w) { return __uint_as_float(w & 0xffff0000u); }

__device__ inline float fast_tanh(float x) {
    // tanh(x) = 1 - 2/(exp(2x)+1); exact at +-inf
    return 1.f - 2.f / (__expf(2.f * x) + 1.f);
}

#define GLOAD_LDS16(gp, lp) __builtin_amdgcn_global_load_lds( \
    (const __attribute__((address_space(1))) void*)(gp),      \
    (__attribute__((address_space(3))) void*)(lp), 16, 0, 0)

// ---------------------------------------------------------------------------
// k1: xp = embeds @ w_ih^T + b_ih + b_hh, written in k2's WG-local layout:
//   xp2[ ((c*16 + slice)*SS + t)*128 + g*32 + (j&31) ]
// (c=chain, t=step, slice=j>>5, g=gate). One contiguous 512B block per
// k2-WG-step.
// ---------------------------------------------------------------------------
__global__ __launch_bounds__(256) void k_embed_xp(
    const int* __restrict__ batch, const float* __restrict__ emb,
    const float* __restrict__ w_ih, const float* __restrict__ b_ih,
    const float* __restrict__ b_hh, float* __restrict__ xp)
{
    __shared__ float Asl[16 * 64];
    __shared__ float Bsl[16 * 64];
    const int tid = threadIdx.x;
    const int bs0 = blockIdx.x * 64;
    const int g0  = blockIdx.y * 64;
    const int m  = tid & 63;
    const int kg = tid >> 6;
    const int tok = batch[bs0 + m];
    const float* arow = emb + (size_t)tok * EMB;
    const float* brow = w_ih + (size_t)(g0 + m) * EMB;
    const int tm = tid >> 4;
    const int tv = tid & 15;

    float acc[4][4] = {};
    for (int k0 = 0; k0 < EMB; k0 += 16) {
        float4 a4 = *(const float4*)(arow + k0 + kg * 4);
        float4 b4 = *(const float4*)(brow + k0 + kg * 4);
        __syncthreads();
        const int kb = kg * 4;
        Asl[(kb + 0) * 64 + m] = a4.x;
        Asl[(kb + 1) * 64 + m] = a4.y;
        Asl[(kb + 2) * 64 + m] = a4.z;
        Asl[(kb + 3) * 64 + m] = a4.w;
        Bsl[(kb + 0) * 64 + m] = b4.x;
        Bsl[(kb + 1) * 64 + m] = b4.y;
        Bsl[(kb + 2) * 64 + m] = b4.z;
        Bsl[(kb + 3) * 64 + m] = b4.w;
        __syncthreads();
#pragma unroll
        for (int k = 0; k < 16; ++k) {
            float4 av = *(const float4*)&Asl[k * 64 + tm * 4];
            float4 bv = *(const float4*)&Bsl[k * 64 + tv * 4];
            float a[4] = {av.x, av.y, av.z, av.w};
            float bb[4] = {bv.x, bv.y, bv.z, bv.w};
#pragma unroll
            for (int i = 0; i < 4; ++i)
#pragma unroll
                for (int j = 0; j < 4; ++j)
                    acc[i][j] += a[i] * bb[j];
        }
    }
    float bsum[4];
#pragma unroll
    for (int j = 0; j < 4; ++j) {
        int g = g0 + tv * 4 + j;
        bsum[j] = b_ih[g] + b_hh[g];
    }
    const int cg = g0 + tv * 4;          // gate-column of element 0
    const int gg = cg >> 9;              // gate 0..3
    const int jj = cg & 511;             // hidden unit
    const int sl = jj >> 5;              // slice
    const int li = jj & 31;              // unit within slice
#pragma unroll
    for (int i = 0; i < 4; ++i) {
        int row = bs0 + tm * 4 + i;
        int cch = row >> 9, tt = row & 511;
        float4 o;
        o.x = acc[i][0] + bsum[0];
        o.y = acc[i][1] + bsum[1];
        o.z = acc[i][2] + bsum[2];
        o.w = acc[i][3] + bsum[3];
        *(float4*)(xp + ((size_t)(cch * 16 + sl) * SS + tt) * 128 +
                   gg * 32 + li) = o;
    }
}

// ---------------------------------------------------------------------------
// k2: persistent LSTM — R3 frame (64 WGs, 2 barriers, wave-0 tail with
// consolidated store burst) + surgical off-wire fixes:
//   * xp read: one contiguous 512B block/WG/step into a register pre-poll
//   * dot: 4 independent accumulators (breaks the 128-fmaf dep chain)
//   * tail: fast_tanh, hw (wire) store issued before hsaveB store
// Thread (r,q): r=tid>>2 gate row 0..127 (g=r>>5, u=r&31), q=tid&3 K-quarter.
// h word = (bf16(h)<<16 | step tag), parity double-buffered; producer does
// ONE fire-and-forget relaxed-agent store burst from wave 0; consumers poll
// the tagged words themselves.
// ---------------------------------------------------------------------------
__global__ __launch_bounds__(512) void k_lstm(
    const float* __restrict__ w_hh, const float* __restrict__ xp2,
    u32* __restrict__ hw, u16* __restrict__ hsaveB)
{
    __shared__ float hl[4 * 132];   // [quarter*132 + idx]; single buffer (safe:
                                    // refills only after the post-gacc barrier)
    __shared__ float gacc[128];

    const int tid   = threadIdx.x;
    const int wg    = blockIdx.x;      // 64 WGs
    const int c     = wg >> 4;         // chain 0..3
    const int slice = wg & 15;
    const int j0    = slice * 32;
    const int r     = tid >> 2;        // gate row in slice 0..127
    const int q     = tid & 3;         // K-quarter
    const int grow  = (r >> 5) * HID + j0 + (r & 31);

    // preload this thread's 128 w_hh values as packed bf16 (64 VGPRs)
    unsigned wreg[64];
    {
        const float* wsrc = w_hh + (size_t)grow * HID + q * 128;
#pragma unroll
        for (int i = 0; i < 32; ++i) {
            float4 f = *(const float4*)(wsrc + i * 4);
            wreg[2 * i]     = packbf(f.x, f.y);
            wreg[2 * i + 1] = packbf(f.z, f.w);
        }
    }

    const float* xbase = xp2 + (size_t)(c * 16 + slice) * (SS * 128) + r;
    float cst = 0.f;                   // cell state (tid<32)

    for (int t = 0; t < SS; ++t) {
        const int p = t & 1;
        // xp gate-bias for row r: contiguous 512B block per WG, issued before
        // the poll; first use is post-dot so the latency is fully hidden.
        float xsv = xbase[t * 128];
        // poll tagged h word for element `tid` of this chain
        u32 w;
        {
            u32* addr = hw + p * (BB * HID) + c * HID + tid;
            int guard = 0;
            for (;;) {
                w = __hip_atomic_load(addr, __ATOMIC_RELAXED,
                                      __HIP_MEMORY_SCOPE_AGENT);
                if ((w & 0xffffu) == (u32)t) break;
                __builtin_amdgcn_s_sleep(1);
                if (++guard > 2000000) break;
            }
        }
        hl[(tid >> 7) * 132 + (tid & 127)] = __uint_as_float(w & 0xffff0000u);
        __syncthreads();

        // 128-element partial dot: row grow, quarter q; 4 independent chains
        float a0 = 0.f, a1 = 0.f, a2 = 0.f, a3 = 0.f;
        {
            const float4* h4 = (const float4*)&hl[q * 132];
#pragma unroll
            for (int k = 0; k < 32; k += 4) {
                float4 v0 = h4[k + 0];
                unsigned wa = wreg[2 * k + 0], wb = wreg[2 * k + 1];
                a0 = fmaf(v0.x, lo16(wa), a0);
                a0 = fmaf(v0.y, hi16(wa), a0);
                a0 = fmaf(v0.z, lo16(wb), a0);
                a0 = fmaf(v0.w, hi16(wb), a0);
                float4 v1 = h4[k + 1];
                wa = wreg[2 * k + 2]; wb = wreg[2 * k + 3];
                a1 = fmaf(v1.x, lo16(wa), a1);
                a1 = fmaf(v1.y, hi16(wa), a1);
                a1 = fmaf(v1.z, lo16(wb), a1);
                a1 = fmaf(v1.w, hi16(wb), a1);
                float4 v2 = h4[k + 2];
                wa = wreg[2 * k + 4]; wb = wreg[2 * k + 5];
                a2 = fmaf(v2.x, lo16(wa), a2);
                a2 = fmaf(v2.y, hi16(wa), a2);
                a2 = fmaf(v2.z, lo16(wb), a2);
                a2 = fmaf(v2.w, hi16(wb), a2);
                float4 v3 = h4[k + 3];
                wa = wreg[2 * k + 6]; wb = wreg[2 * k + 7];
                a3 = fmaf(v3.x, lo16(wa), a3);
                a3 = fmaf(v3.y, hi16(wa), a3);
                a3 = fmaf(v3.z, lo16(wb), a3);
                a3 = fmaf(v3.w, hi16(wb), a3);
            }
        }
        float acc = (a0 + a1) + (a2 + a3);
        // reduce the 4 K-quarters (lanes q=0..3 adjacent)
        acc += __shfl_xor(acc, 1);
        acc += __shfl_xor(acc, 2);
        if (q == 0) gacc[r] = acc + xsv;
        __syncthreads();

        if (tid < 32) {
            float iv = gacc[tid],      fv = gacc[32 + tid];
            float gv = gacc[64 + tid], ov = gacc[96 + tid];
            float si = 1.f / (1.f + __expf(-iv));
            float sf = 1.f / (1.f + __expf(-fv));
            float so = 1.f / (1.f + __expf(-ov));
            cst = sf * cst + si * fast_tanh(gv);
            float hv = so * fast_tanh(cst);
            unsigned uu = __float_as_uint(hv);
            uu += 0x7fffu + ((uu >> 16) & 1u);
            uu &= 0xffff0000u;         // bf16 bits in hi16
            // wire word first (consumers poll this), then the archive store
            __hip_atomic_store(hw + (p ^ 1) * (BB * HID) + c * HID + j0 + tid,
                               uu | (u32)(t + 1), __ATOMIC_RELAXED,
                               __HIP_MEMORY_SCOPE_AGENT);
            hsaveB[(size_t)(c * SS + t) * HID + j0 + tid] = (u16)(uu >> 16);
        }
        // no trailing barrier: hl refill at t+1 happens only after this
        // step's post-gacc barrier; tail reads gacc only, and gacc rewrite
        // at t+1 requires wave 0 (tail owner) to pass t+1's first barrier.
    }
}

// ---------------------------------------------------------------------------
// wcvt: W fp32 -> bf16 (RNE), 16.384M elems
// ---------------------------------------------------------------------------
__global__ __launch_bounds__(256) void k_wcvt(
    const float* __restrict__ W, u16* __restrict__ WB)
{
    int i = blockIdx.x * 256 + threadIdx.x;
    float4 f = ((const float4*)W)[i];
    uint2 o;
    o.x = packbf(f.x, f.y);
    o.y = packbf(f.z, f.w);
    ((uint2*)WB)[i] = o;
}

// ---------------------------------------------------------------------------
// k3: bf16 MFMA logits + fused exp/row-sum -> sumexp.
// 128x128 tile, BK=64, global_load_lds(16B) with chunk-XOR swizzle.
// ---------------------------------------------------------------------------
__global__ __launch_bounds__(256) void k_logits_lse(
    const u16* __restrict__ hsaveB, const u16* __restrict__ WB,
    const float* __restrict__ bias, float* __restrict__ sumexp)
{
    __shared__ u16 As[128 * 64];
    __shared__ u16 Bs[128 * 64];
    const int tid  = threadIdx.x;
    const int lane = tid & 63;
    const int wave = tid >> 6;
    const int wr   = wave >> 1;
    const int wc   = wave & 1;
    const int bs0  = blockIdx.x * 128;
    const int v0   = blockIdx.y * 128;
    const int lr   = lane & 15;
    const int lc   = lane >> 4;

    f32x4 acc[4][4];
#pragma unroll
    for (int m = 0; m < 4; ++m)
#pragma unroll
        for (int n = 0; n < 4; ++n)
            acc[m][n] = (f32x4){0.f, 0.f, 0.f, 0.f};

    for (int k0 = 0; k0 < HID; k0 += 64) {
#pragma unroll
        for (int it = 0; it < 4; ++it) {
            int base = it * 256 + wave * 64;
            int idx  = base + lane;
            int row  = idx >> 3, cl = idx & 7;
            int gcl  = cl ^ (row & 7);
            const u16* gA = hsaveB + (size_t)(bs0 + row) * HID + k0 + gcl * 8;
            GLOAD_LDS16(gA, As + (size_t)base * 8);
            const u16* gB = WB + (size_t)(v0 + row) * HID + k0 + gcl * 8;
            GLOAD_LDS16(gB, Bs + (size_t)base * 8);
        }
        asm volatile("s_waitcnt vmcnt(0)" ::: "memory");
        __syncthreads();

        short8 af[4][2], bf[4][2];
#pragma unroll
        for (int m = 0; m < 4; ++m)
#pragma unroll
            for (int ks = 0; ks < 2; ++ks) {
                int rowA = wr * 64 + m * 16 + lr;
                int swa  = ((ks * 4 + lc) ^ (rowA & 7)) * 8;
                af[m][ks] = *(const short8*)&As[rowA * 64 + swa];
                int rowB = wc * 64 + m * 16 + lr;
                int swb  = ((ks * 4 + lc) ^ (rowB & 7)) * 8;
                bf[m][ks] = *(const short8*)&Bs[rowB * 64 + swb];
            }
#pragma unroll
        for (int m = 0; m < 4; ++m)
#pragma unroll
            for (int n = 0; n < 4; ++n)
#pragma unroll
                for (int ks = 0; ks < 2; ++ks)
                    acc[m][n] = __builtin_amdgcn_mfma_f32_16x16x32_bf16(
                        af[m][ks], bf[n][ks], acc[m][n], 0, 0, 0);
        __syncthreads();
    }

    float bn[4];
#pragma unroll
    for (int n = 0; n < 4; ++n)
        bn[n] = bias[v0 + wc * 64 + n * 16 + lr];

#pragma unroll
    for (int m = 0; m < 4; ++m) {
        float p0 = 0.f, p1 = 0.f, p2 = 0.f, p3 = 0.f;
#pragma unroll
        for (int n = 0; n < 4; ++n) {
            float b = bn[n];
            p0 += __expf(acc[m][n][0] + b);
            p1 += __expf(acc[m][n][1] + b);
            p2 += __expf(acc[m][n][2] + b);
            p3 += __expf(acc[m][n][3] + b);
        }
#pragma unroll
        for (int off = 1; off < 16; off <<= 1) {
            p0 += __shfl_xor(p0, off);
            p1 += __shfl_xor(p1, off);
            p2 += __shfl_xor(p2, off);
            p3 += __shfl_xor(p3, off);
        }
        if (lr == 0) {
            int row = bs0 + wr * 64 + m * 16 + lc * 4;
            atomicAdd(&sumexp[row + 0], p0);
            atomicAdd(&sumexp[row + 1], p1);
            atomicAdd(&sumexp[row + 2], p2);
            atomicAdd(&sumexp[row + 3], p3);
        }
    }
}

// ---------------------------------------------------------------------------
// k4: one wave per (b,s): decode contiguous-view gather, recompute picked
// logit (bf16), subtract log(sumexp), accumulate -mean.
// ---------------------------------------------------------------------------
__device__ inline float dotp(u32 h, u32 w) {
    return __uint_as_float(h << 16) * __uint_as_float(w << 16) +
           __uint_as_float(h & 0xffff0000u) * __uint_as_float(w & 0xffff0000u);
}

__global__ __launch_bounds__(256) void k_final(
    const int* __restrict__ batch, const u16* __restrict__ hsaveB,
    const u16* __restrict__ WB, const float* __restrict__ bias,
    const float* __restrict__ sumexp, float* __restrict__ out)
{
    const int gt   = blockIdx.x * 256 + threadIdx.x;
    const int wid  = gt >> 6;
    const int lane = gt & 63;
    const unsigned tgt = (unsigned)batch[wid];
    const unsigned s2 = wid >> 2, b2 = wid & 3;
    const unsigned j = s2 * (VOCAB * BB) + tgt * BB + b2;
    const unsigned SV = (unsigned)SS * VOCAB;
    const unsigned b_o = j / SV;
    const unsigned rr = j - b_o * SV;
    const unsigned s_o = rr / VOCAB;
    const unsigned v_o = rr - s_o * VOCAB;
    const unsigned row = b_o * SS + s_o;

    uint4 hu = *(const uint4*)(hsaveB + (size_t)row * HID + lane * 8);
    uint4 wu = *(const uint4*)(WB + (size_t)v_o * HID + lane * 8);
    float d = dotp(hu.x, wu.x) + dotp(hu.y, wu.y) +
              dotp(hu.z, wu.z) + dotp(hu.w, wu.w);
#pragma unroll
    for (int off = 32; off >= 1; off >>= 1)
        d += __shfl_xor(d, off);
    if (lane == 0) {
        float picked = d + bias[v_o] - logf(sumexp[row]);
        atomicAdd(out, -picked * (1.f / (float)BS));
    }
}

// ---------------------------------------------------------------------------
extern "C" void kernel_launch(void* const* d_in, const int* in_sizes, int n_in,
                              void* d_out, int out_size, void* d_ws, size_t ws_size,
                              hipStream_t stream)
{
    const int*   batch = (const int*)d_in[0];
    const float* emb   = (const float*)d_in[1];
    const float* w_ih  = (const float*)d_in[2];
    const float* w_hh  = (const float*)d_in[3];
    const float* b_ih  = (const float*)d_in[4];
    const float* b_hh  = (const float*)d_in[5];
    const float* Wm    = (const float*)d_in[6];
    const float* bvec  = (const float*)d_in[7];
    float* out = (float*)d_out;
    float* ws  = (float*)d_ws;

    float* xp      = ws;                       // dead after k2
    u16*   WB      = (u16*)ws;                 // written after k2 (time-shared)
    u16*   hsaveB  = (u16*)(ws + OFF_HSB);
    u32*   hw      = (u32*)(ws + OFF_HW);
    float* sumexp  = ws + OFF_SUM;

    // zero hw (+slack) + sumexp (contiguous) and out
    hipMemsetAsync(hw, 0, (4096 + 2048 + 2048) * sizeof(float), stream);
    hipMemsetAsync(out, 0, sizeof(float), stream);

    dim3 g1(BS / 64, G4H / 64);
    k_embed_xp<<<g1, 256, 0, stream>>>(batch, emb, w_ih, b_ih, b_hh, xp);

    k_lstm<<<64, 512, 0, stream>>>(w_hh, xp, hw, hsaveB);

    k_wcvt<<<VOCAB * HID / 4 / 256, 256, 0, stream>>>(Wm, WB);

    dim3 g3(BS / 128, VOCAB / 128);
    k_logits_lse<<<g3, 256, 0, stream>>>(hsaveB, WB, bvec, sumexp);

    k_final<<<BS * 64 / 256, 256, 0, stream>>>(batch, hsaveB, WB, bvec, sumexp, out);
}